// Round 4
// baseline (367.052 us; speedup 1.0000x reference)
//
#include <hip/hip_runtime.h>
#include <float.h>
#include <math.h>

#define B_  8
#define H_  8
#define L_  2048
#define D_  64
#define NS  40          // num selected = min(5*ceil(ln(2048)), 2048) = 40
#define BH  (B_*H_)
#define SCALE 0.125f    // d^-0.5

// XCD swizzle: MI355X dispatches block b to XCD (b % 8).  We remap so that
// bh % 8 == b % 8 for every kernel -> all blocks of one bh run on one XCD,
// keeping that bh's k/v/measure/attn slices resident in its 4MB L2.

// DPP helper: x += lane_shifted_down_by<SHR>(x), within rows of 16 lanes,
// out-of-row reads return 0 (bound_ctrl).  Pure VALU - no LDS pipe.
template<int CTRL>
__device__ __forceinline__ float dpp_add(float x) {
    int s = __builtin_amdgcn_update_dpp(0, __float_as_int(x), CTRL, 0xF, 0xF, true);
    return x + __int_as_float(s);
}

// ---------------------------------------------------------------------------
// K1: sparsity measure.  One wave per query.  Octet (8 lanes x 2 f4) reads one
// k row; 5 passes cover 40 samples.
//  R6: measure is TA-throughput-bound (~16 cy per VMEM instr regardless of
//  coalescing; 18 instrs/wave ~= 288 cy * 512 waves/CU ~= observed 78us).
//  Cut VMEM 18 -> 15: octet o now owns samples {4o..4o+3, 32+o}, so ridx
//  loads collapse from 5 scalar dwords to 1 aligned int4 + 1 int.
//  (sample->octet assignment is arbitrary: max/sum are commutative)
// ---------------------------------------------------------------------------
__global__ __launch_bounds__(256) void measure_kernel(
    const float* __restrict__ q, const float* __restrict__ k,
    const int* __restrict__ ridx, float* __restrict__ measure)
{
    int wave = threadIdx.x >> 6, lane = threadIdx.x & 63;
    int b = blockIdx.x;
    int xcd = b & 7, s = b >> 3;          // s in 0..4095
    int bh  = xcd + ((s >> 9) << 3);      // 8 bh per XCD, sequential
    int i   = (s & 511) * 4 + wave;       // query row within bh
    int oct = lane >> 3;                  // octet id 0..7 (row owner)
    int e   = lane & 7;                   // f4 slot within half-row

    // octet o handles samples 4o..4o+3 (one aligned int4) and 32+o (int).
    // 160B*i + 16B*o is 16B-aligned.
    int4 r4 = *(const int4*)(ridx + i * NS + oct * 4);
    int  r5 = ridx[i * NS + 32 + oct];
    int rr[5] = { r4.x, r4.y, r4.z, r4.w, r5 };

    const float4* kb = (const float4*)(k + (size_t)bh * L_ * D_);
    const float4* qp = (const float4*)(q + ((size_t)bh * L_ + i) * D_);
    float4 qa = qp[e];          // dims 4e .. 4e+3
    float4 qb = qp[e + 8];      // dims 32+4e .. 32+4e+3

    float mx = -FLT_MAX, sm = 0.f;
    #pragma unroll
    for (int p = 0; p < 5; ++p) {
        int base = rr[p] << 4;                   // f4 index of row start
        float4 ka = kb[base + e];                // 8 lanes cover half the row
        float4 kc = kb[base + 8 + e];            // ... and the other half
        float pa = qa.x*ka.x + qa.y*ka.y + qa.z*ka.z + qa.w*ka.w;
        float pb = qb.x*kc.x + qb.y*kc.y + qb.z*kc.z + qb.w*kc.w;
        float pp = pa + pb;                      // 8-dim partial per lane
        // octet tree-sum: after shr1/2/4, lane 8o+7 = full dot(q, k[r])
        pp = dpp_add<0x111>(pp);                 // row_shr:1
        pp = dpp_add<0x112>(pp);                 // row_shr:2
        pp = dpp_add<0x114>(pp);                 // row_shr:4
        mx = fmaxf(mx, pp);                      // valid only in holder lanes
        sm += pp;
    }
    // holder lanes {7,15,...,63} each carry stats over their 5 samples;
    // xor partners of holders are holders, so 3 xor steps combine all 8.
    mx = fmaxf(mx, __shfl_xor(mx,  8, 64));  sm += __shfl_xor(sm,  8, 64);
    mx = fmaxf(mx, __shfl_xor(mx, 16, 64));  sm += __shfl_xor(sm, 16, 64);
    mx = fmaxf(mx, __shfl_xor(mx, 32, 64));  sm += __shfl_xor(sm, 32, 64);
    if (lane == 7)
        measure[(size_t)bh * L_ + i] = mx - sm * (1.0f / (float)L_);
}

// ---------------------------------------------------------------------------
// K2: top-NS per (b,h).  R6: single-wave block, fully register-resident,
// ZERO barriers (was 256 threads with 3 syncthreads x 40 rounds).
// Lane ell holds 32 values; global index of vals[g*4+c] = 256g + 4*ell + c.
// Ties: lower index (lax.top_k).
// ---------------------------------------------------------------------------
__global__ __launch_bounds__(64) void topk_kernel(
    const float* __restrict__ measure, int* __restrict__ idxOut)
{
    int bh = blockIdx.x;                  // b%8 == bh%8: same L2 as producer
    int lane = threadIdx.x;               // 0..63
    const float4* m4 = (const float4*)(measure + (size_t)bh * L_);
    float vals[32];
    #pragma unroll
    for (int g = 0; g < 8; ++g) {
        float4 x = m4[g*64 + lane];       // coalesced
        vals[g*4+0]=x.x; vals[g*4+1]=x.y; vals[g*4+2]=x.z; vals[g*4+3]=x.w;
    }

    float lv = -FLT_MAX; int li = 0x7fffffff;
    #pragma unroll
    for (int g = 0; g < 8; ++g)
        #pragma unroll
        for (int c = 0; c < 4; ++c) {
            int gi = 256*g + 4*lane + c;
            float x = vals[g*4+c];
            if (x > lv || (x == lv && gi < li)) { lv = x; li = gi; }
        }

    for (int r = 0; r < NS; ++r) {
        float v = lv; int idx = li;
        #pragma unroll
        for (int off = 32; off; off >>= 1) {       // butterfly: all lanes get winner
            float ov = __shfl_xor(v, off, 64);
            int   oi = __shfl_xor(idx, off, 64);
            if (ov > v || (ov == v && oi < idx)) { v = ov; idx = oi; }
        }
        if (lane == 0) idxOut[bh*NS + r] = idx;
        // winner's owner lane invalidates it and recomputes its local max
        if (((idx >> 2) & 63) == lane) {
            int slot = ((idx >> 8) << 2) | (idx & 3);   // g*4 + c
            #pragma unroll
            for (int ss = 0; ss < 32; ++ss)             // static idx: stays in regs
                if (ss == slot) vals[ss] = -FLT_MAX;
            lv = -FLT_MAX; li = 0x7fffffff;
            #pragma unroll
            for (int g = 0; g < 8; ++g)
                #pragma unroll
                for (int c = 0; c < 4; ++c) {
                    int gi = 256*g + 4*lane + c;
                    float x = vals[g*4+c];
                    if (x > lv || (x == lv && gi < li)) { lv = x; li = gi; }
                }
        }
    }
}

// ---------------------------------------------------------------------------
// K3: cumsum(v) along L, two passes, 1024 blocks each, XCD-swizzled.
// ---------------------------------------------------------------------------
__global__ __launch_bounds__(256) void cumsum_p1(
    const float* __restrict__ v, float4* __restrict__ vpart)
{
    __shared__ float4 part[16][16];
    int b = blockIdx.x;
    int xcd = b & 7, s = b >> 3;          // s in 0..127
    int bh = xcd + ((s >> 4) << 3);
    int c  = s & 15;
    int d4 = threadIdx.x & 15, sub = threadIdx.x >> 4;
    const float4* vb = (const float4*)(v + (size_t)bh * L_ * D_);
    int r0 = c*128 + sub*8;
    float4 acc = make_float4(0,0,0,0);
    #pragma unroll
    for (int r = 0; r < 8; ++r) {
        float4 x = vb[(r0 + r)*16 + d4];
        acc.x += x.x; acc.y += x.y; acc.z += x.z; acc.w += x.w;
    }
    part[sub][d4] = acc;
    __syncthreads();
    if (sub == 0) {
        float4 tot = part[0][d4];
        #pragma unroll
        for (int ss = 1; ss < 16; ++ss) {
            float4 x = part[ss][d4];
            tot.x += x.x; tot.y += x.y; tot.z += x.z; tot.w += x.w;
        }
        vpart[(bh*16 + c)*16 + d4] = tot;
    }
}

__global__ __launch_bounds__(256) void cumsum_p2(
    const float* __restrict__ v, const float4* __restrict__ vpart,
    float* __restrict__ out)
{
    __shared__ float4 part[16][16];
    int b = blockIdx.x;
    int xcd = b & 7, s = b >> 3;
    int bh = xcd + ((s >> 4) << 3);
    int c  = s & 15;
    int d4 = threadIdx.x & 15, sub = threadIdx.x >> 4;
    const float4* vb = (const float4*)(v + (size_t)bh * L_ * D_);
    float4*       ob = (float4*)(out + (size_t)bh * L_ * D_);
    int r0 = c*128 + sub*8;
    float4 acc = make_float4(0,0,0,0);
    #pragma unroll
    for (int r = 0; r < 8; ++r) {
        float4 x = vb[(r0 + r)*16 + d4];
        acc.x += x.x; acc.y += x.y; acc.z += x.z; acc.w += x.w;
    }
    part[sub][d4] = acc;
    float4 run = make_float4(0,0,0,0);
    for (int cc = 0; cc < c; ++cc) {
        float4 x = vpart[(bh*16 + cc)*16 + d4];
        run.x += x.x; run.y += x.y; run.z += x.z; run.w += x.w;
    }
    __syncthreads();
    #pragma unroll
    for (int ss = 0; ss < 16; ++ss) {
        if (ss < sub) {
            float4 x = part[ss][d4];
            run.x += x.x; run.y += x.y; run.z += x.z; run.w += x.w;
        }
    }
    #pragma unroll
    for (int r = 0; r < 8; ++r) {
        float4 x = vb[(r0 + r)*16 + d4];
        run.x += x.x; run.y += x.y; run.z += x.z; run.w += x.w;
        ob[(r0 + r)*16 + d4] = run;
    }
}

// ---------------------------------------------------------------------------
// K4a: scores + softmax fused.  Block = (bh, group of 4 ranks), one wave per
// rank, XCD-swizzled (k slice L2-resident).  Writes normalized weights
// (zeros past qrow).
// ---------------------------------------------------------------------------
__global__ __launch_bounds__(256) void scores_kernel(
    const float* __restrict__ q, const float* __restrict__ k,
    const int* __restrict__ idxSel, float* __restrict__ attn)
{
    __shared__ float4 kbuf[16 * 129];   // [g][j], stride 129 f4
    int b = blockIdx.x;
    int xcd = b & 7, s = b >> 3;          // s in 0..79
    int bh  = xcd + ((s / 10) << 3);
    int grp = s % 10;
    int qi = threadIdx.x >> 6, sub = threadIdx.x & 63;
    int rank = grp*4 + qi;
    int qrow = idxSel[bh*NS + rank];

    const float4* qrp = (const float4*)(q + ((size_t)bh * L_ + qrow) * D_);
    float4 qreg[16];
    #pragma unroll
    for (int g = 0; g < 16; ++g) qreg[g] = qrp[g];    // wave-uniform

    const float4* kb = (const float4*)(k + (size_t)bh * L_ * D_);
    float sc0[16], sc1[16];

    #pragma unroll
    for (int c = 0; c < 16; ++c) {
        __syncthreads();                               // kbuf reuse guard
        int j0 = c * 128;
        #pragma unroll
        for (int it = 0; it < 8; ++it) {               // coalesced stage
            int fi = threadIdx.x + 256*it;
            int g = fi & 15, j = fi >> 4;
            kbuf[g*129 + j] = kb[(size_t)(j0 + j)*16 + g];
        }
        __syncthreads();
        float acc0 = 0.f, acc1 = 0.f;
        #pragma unroll
        for (int g = 0; g < 16; ++g) {
            float4 k0 = kbuf[g*129 + sub];             // dense b128
            float4 k1 = kbuf[g*129 + sub + 64];
            float4 qq = qreg[g];
            acc0 += qq.x*k0.x + qq.y*k0.y + qq.z*k0.z + qq.w*k0.w;
            acc1 += qq.x*k1.x + qq.y*k1.y + qq.z*k1.z + qq.w*k1.w;
        }
        sc0[c] = acc0 * SCALE;
        sc1[c] = acc1 * SCALE;
    }

    // masked softmax, wave-local (row lives in sc0/sc1)
    float mx = -FLT_MAX;
    #pragma unroll
    for (int c = 0; c < 16; ++c) {
        if (c*128 + sub      <= qrow) mx = fmaxf(mx, sc0[c]);
        if (c*128 + sub + 64 <= qrow) mx = fmaxf(mx, sc1[c]);
    }
    #pragma unroll
    for (int off = 32; off; off >>= 1) mx = fmaxf(mx, __shfl_xor(mx, off, 64));

    float sum = 0.f;
    #pragma unroll
    for (int c = 0; c < 16; ++c) {
        sc0[c] = (c*128 + sub      <= qrow) ? __expf(sc0[c] - mx) : 0.f;
        sc1[c] = (c*128 + sub + 64 <= qrow) ? __expf(sc1[c] - mx) : 0.f;
        sum += sc0[c] + sc1[c];
    }
    #pragma unroll
    for (int off = 32; off; off >>= 1) sum += __shfl_xor(sum, off, 64);
    float inv = 1.f / sum;

    float* arow = attn + (size_t)(bh*NS + rank) * L_;
    #pragma unroll
    for (int c = 0; c < 16; ++c) {
        arow[c*128 + sub]      = sc0[c] * inv;         // coalesced
        arow[c*128 + sub + 64] = sc1[c] * inv;
    }
}

// ---------------------------------------------------------------------------
// K4b: out[bh, qrow_r, :] = attn_row_r @ v for 4 ranks per block,
// XCD-swizzled (v + attn slices L2-resident).
// ---------------------------------------------------------------------------
__global__ __launch_bounds__(256) void pv_kernel(
    const float* __restrict__ v, const int* __restrict__ idxSel,
    const float* __restrict__ attn, float* __restrict__ out)
{
    __shared__ float wl[4][L_ + 64];    // per-rank weights, j + 4*(j>>7) pad
    __shared__ float4 part[16][16];
    __shared__ int qr4[4];
    int b = blockIdx.x;
    int xcd = b & 7, s = b >> 3;          // s in 0..79
    int bh  = xcd + ((s / 10) << 3);
    int grp = s % 10;
    int t = threadIdx.x;
    if (t < 4) qr4[t] = idxSel[bh*NS + grp*4 + t];

    // stage 4 weight rows (coalesced f4 loads)
    #pragma unroll
    for (int it = 0; it < 8; ++it) {
        int f = t + 256*it;             // 0..2047 f4 across 4 rows
        int rr = f >> 9, fi = f & 511;
        const float4* ar = (const float4*)(attn + (size_t)(bh*NS + grp*4 + rr) * L_);
        float4 x = ar[fi];
        int j = 4*fi;
        *((float4*)&wl[rr][j + 4*(j >> 7)]) = x;
    }
    __syncthreads();

    int maxq = max(max(qr4[0], qr4[1]), max(qr4[2], qr4[3]));
    int d4 = t & 15, seg = t >> 4;
    const float4* vb = (const float4*)(v + (size_t)bh * L_ * D_);
    float4 acc[4];
    #pragma unroll
    for (int rr = 0; rr < 4; ++rr) acc[rr] = make_float4(0,0,0,0);

    int jlo = seg*128, jhi = min(jlo + 127, maxq);
    for (int j = jlo; j <= jhi; ++j) {
        float4 x = vb[(size_t)j*16 + d4];          // read once
        int jp = j + 4*(j >> 7);
        #pragma unroll
        for (int rr = 0; rr < 4; ++rr) {
            float wgt = wl[rr][jp];                // 2-way conflict (free)
            acc[rr].x += wgt*x.x; acc[rr].y += wgt*x.y;
            acc[rr].z += wgt*x.z; acc[rr].w += wgt*x.w;
        }
    }

    #pragma unroll
    for (int rr = 0; rr < 4; ++rr) {
        part[seg][d4] = acc[rr];
        __syncthreads();
        float4 a = acc[rr];
        for (int s2 = 8; s2; s2 >>= 1) {
            if (seg < s2) {
                float4 o = part[seg + s2][d4];
                a.x += o.x; a.y += o.y; a.z += o.z; a.w += o.w;
                part[seg][d4] = a;
            }
            __syncthreads();
        }
        if (seg == 0) {
            float4* orow = (float4*)(out + ((size_t)bh * L_ + qr4[rr]) * D_);
            orow[d4] = a;
        }
        __syncthreads();                // before part reuse
    }
}

// ---------------------------------------------------------------------------
extern "C" void kernel_launch(void* const* d_in, const int* in_sizes, int n_in,
                              void* d_out, int out_size, void* d_ws, size_t ws_size,
                              hipStream_t stream) {
    const float* q    = (const float*)d_in[0];
    const float* k    = (const float*)d_in[1];
    const float* v    = (const float*)d_in[2];
    const int*   ridx = (const int*)d_in[3];

    float* out     = (float*)d_out;                    // (B,H,L,D)
    float* attnOut = out + (size_t)BH * L_ * D_;       // (B,H,NS,L)

    float*  measure = (float*)d_ws;                                          // BH*L floats
    int*    idxSel  = (int*)((char*)d_ws + (size_t)BH * L_ * sizeof(float)); // BH*NS ints
    float4* vpart   = (float4*)d_ws;   // aliases measure: only used AFTER topk

    measure_kernel<<<BH * L_ / 4, 256, 0, stream>>>(q, k, ridx, measure);
    topk_kernel   <<<BH,           64, 0, stream>>>(measure, idxSel);
    cumsum_p1     <<<BH * 16,     256, 0, stream>>>(v, vpart);
    cumsum_p2     <<<BH * 16,     256, 0, stream>>>(v, vpart, out);
    scores_kernel <<<BH * 10,     256, 0, stream>>>(q, k, idxSel, attnOut);
    pv_kernel     <<<BH * 10,     256, 0, stream>>>(v, idxSel, attnOut, out);
}

// Round 5
// 325.920 us; speedup vs baseline: 1.1262x; 1.1262x over previous
//
#include <hip/hip_runtime.h>
#include <float.h>
#include <math.h>

#define B_  8
#define H_  8
#define L_  2048
#define D_  64
#define NS  40          // num selected = min(5*ceil(ln(2048)), 2048) = 40
#define BH  (B_*H_)
#define SCALE 0.125f    // d^-0.5

// XCD swizzle: MI355X dispatches block b to XCD (b % 8).  We remap so that
// bh % 8 == b % 8 for every kernel -> all blocks of one bh run on one XCD,
// keeping that bh's k/v/measure/attn slices resident in its 4MB L2.

// DPP helper: x += lane_shifted_down_by<SHR>(x), within rows of 16 lanes,
// out-of-row reads return 0 (bound_ctrl).  Pure VALU - no LDS pipe.
template<int CTRL>
__device__ __forceinline__ float dpp_add(float x) {
    int s = __builtin_amdgcn_update_dpp(0, __float_as_int(x), CTRL, 0xF, 0xF, true);
    return x + __int_as_float(s);
}

// ---------------------------------------------------------------------------
// K1: sparsity measure.  One wave per query.  Octet (8 lanes x 2 f4) reads one
// k row; 5 passes cover 40 samples.  TA-throughput-bound (~16cy/VMEM instr):
// 15 VMEM/wave (1 int4 + 1 int ridx, 2 q, 10 gathers [packing-optimal:
// 40 rows x 256B / 1KB-per-instr = 10], 1 store).
// ---------------------------------------------------------------------------
__global__ __launch_bounds__(256) void measure_kernel(
    const float* __restrict__ q, const float* __restrict__ k,
    const int* __restrict__ ridx, float* __restrict__ measure)
{
    int wave = threadIdx.x >> 6, lane = threadIdx.x & 63;
    int b = blockIdx.x;
    int xcd = b & 7, s = b >> 3;          // s in 0..4095
    int bh  = xcd + ((s >> 9) << 3);      // 8 bh per XCD, sequential
    int i   = (s & 511) * 4 + wave;       // query row within bh
    int oct = lane >> 3;                  // octet id 0..7 (row owner)
    int e   = lane & 7;                   // f4 slot within half-row

    // octet o handles samples 4o..4o+3 (one aligned int4) and 32+o (int).
    // 160B*i + 16B*o is 16B-aligned.
    int4 r4 = *(const int4*)(ridx + i * NS + oct * 4);
    int  r5 = ridx[i * NS + 32 + oct];
    int rr[5] = { r4.x, r4.y, r4.z, r4.w, r5 };

    const float4* kb = (const float4*)(k + (size_t)bh * L_ * D_);
    const float4* qp = (const float4*)(q + ((size_t)bh * L_ + i) * D_);
    float4 qa = qp[e];          // dims 4e .. 4e+3
    float4 qb = qp[e + 8];      // dims 32+4e .. 32+4e+3

    float mx = -FLT_MAX, sm = 0.f;
    #pragma unroll
    for (int p = 0; p < 5; ++p) {
        int base = rr[p] << 4;                   // f4 index of row start
        float4 ka = kb[base + e];                // 8 lanes cover half the row
        float4 kc = kb[base + 8 + e];            // ... and the other half
        float pa = qa.x*ka.x + qa.y*ka.y + qa.z*ka.z + qa.w*ka.w;
        float pb = qb.x*kc.x + qb.y*kc.y + qb.z*kc.z + qb.w*kc.w;
        float pp = pa + pb;                      // 8-dim partial per lane
        // octet tree-sum: after shr1/2/4, lane 8o+7 = full dot(q, k[r])
        pp = dpp_add<0x111>(pp);                 // row_shr:1
        pp = dpp_add<0x112>(pp);                 // row_shr:2
        pp = dpp_add<0x114>(pp);                 // row_shr:4
        mx = fmaxf(mx, pp);                      // valid only in holder lanes
        sm += pp;
    }
    // holder lanes {7,15,...,63} each carry stats over their 5 samples;
    // xor partners of holders are holders, so 3 xor steps combine all 8.
    mx = fmaxf(mx, __shfl_xor(mx,  8, 64));  sm += __shfl_xor(sm,  8, 64);
    mx = fmaxf(mx, __shfl_xor(mx, 16, 64));  sm += __shfl_xor(sm, 16, 64);
    mx = fmaxf(mx, __shfl_xor(mx, 32, 64));  sm += __shfl_xor(sm, 32, 64);
    if (lane == 7)
        measure[(size_t)bh * L_ + i] = mx - sm * (1.0f / (float)L_);
}

// ---------------------------------------------------------------------------
// K2: top-NS per (b,h), register-resident.  Ties: lower index (lax.top_k).
// R7: REVERTED to the 256-thread barrier version.  The single-wave rewrite
// (R6) was a pure latency chain on 64 CUs: 83us vs ~10us for this one.
// ---------------------------------------------------------------------------
__global__ __launch_bounds__(256) void topk_kernel(
    const float* __restrict__ measure, int* __restrict__ idxOut)
{
    __shared__ float wv[4]; __shared__ int wi[4];
    __shared__ float bvS;   __shared__ int biS;
    int b = blockIdx.x;
    int bh = (b & 7) + ((b >> 3) << 3);   // identity, but keeps mapping explicit
    int t = threadIdx.x;
    const float4* m4 = (const float4*)(measure + (size_t)bh * L_);
    float vals[8];
    float4 a = m4[t*2], bb = m4[t*2 + 1];
    vals[0]=a.x; vals[1]=a.y; vals[2]=a.z; vals[3]=a.w;
    vals[4]=bb.x; vals[5]=bb.y; vals[6]=bb.z; vals[7]=bb.w;

    float lv = -FLT_MAX; int li = t*8;
    #pragma unroll
    for (int e = 0; e < 8; ++e) if (vals[e] > lv) { lv = vals[e]; li = t*8 + e; }

    int lane = t & 63, w = t >> 6;
    for (int r = 0; r < NS; ++r) {
        float v = lv; int idx = li;
        #pragma unroll
        for (int off = 32; off; off >>= 1) {
            float ov = __shfl_xor(v, off, 64);
            int   oi = __shfl_xor(idx, off, 64);
            if (ov > v || (ov == v && oi < idx)) { v = ov; idx = oi; }
        }
        if (lane == 0) { wv[w] = v; wi[w] = idx; }
        __syncthreads();
        if (t == 0) {
            float bv = wv[0]; int bi = wi[0];
            #pragma unroll
            for (int ww = 1; ww < 4; ++ww)
                if (wv[ww] > bv || (wv[ww] == bv && wi[ww] < bi)) { bv = wv[ww]; bi = wi[ww]; }
            bvS = bv; biS = bi;
            idxOut[bh * NS + r] = bi;
        }
        __syncthreads();
        int bi = biS;
        if ((bi >> 3) == t) {
            #pragma unroll
            for (int e = 0; e < 8; ++e) if ((bi & 7) == e) vals[e] = -FLT_MAX;
            lv = -FLT_MAX; li = t*8;
            #pragma unroll
            for (int e = 0; e < 8; ++e) if (vals[e] > lv) { lv = vals[e]; li = t*8 + e; }
        }
        __syncthreads();
    }
}

// ---------------------------------------------------------------------------
// K3: cumsum(v) along L.  R7: FUSED single kernel, 256 blocks = bh x 4
// column-groups (4 f4 cols each), XCD-swizzled.  Each thread owns a 32-row
// stripe of one f4 column: stripe-total -> LDS -> exclusive prefix over the
// 64 stripes -> re-read (L3-resident) with running-sum store.  Replaces the
// two-pass version: ~6.3M vs ~10.4M VMEM instr-lanes, one fewer launch, no
// vpart round-trip.  Same summation order as the 2-pass version (partials
// then sequential) -> same numerics.
// ---------------------------------------------------------------------------
__global__ __launch_bounds__(256) void cumsum_fused(
    const float* __restrict__ v, float* __restrict__ out)
{
    __shared__ float4 part[64][5];        // [sub][col], pad 4->5 (bank spread)
    int b = blockIdx.x;
    int xcd = b & 7, s = b >> 3;          // s in 0..31
    int bh  = xcd + ((s >> 2) << 3);      // 8 bh per XCD
    int cg  = s & 3;                      // column group: f4 cols 4cg..4cg+3
    int col = threadIdx.x & 3, sub = threadIdx.x >> 2;   // sub 0..63
    int c0 = cg*4 + col;                  // f4 column 0..15
    int r0 = sub * 32;                    // stripe start row
    const float4* vb = (const float4*)(v + (size_t)bh * L_ * D_);
    float4*       ob = (float4*)(out + (size_t)bh * L_ * D_);

    float4 acc = make_float4(0,0,0,0);
    #pragma unroll
    for (int r = 0; r < 32; ++r) {        // 4 lanes/row = aligned 64B segments
        float4 x = vb[(size_t)(r0 + r)*16 + c0];
        acc.x += x.x; acc.y += x.y; acc.z += x.z; acc.w += x.w;
    }
    part[sub][col] = acc;
    __syncthreads();

    float4 run = make_float4(0,0,0,0);    // exclusive prefix of stripes 0..sub-1
    for (int cc = 0; cc < sub; ++cc) {    // 16-lane broadcast reads: conflict-free
        float4 x = part[cc][col];
        run.x += x.x; run.y += x.y; run.z += x.z; run.w += x.w;
    }

    #pragma unroll
    for (int r = 0; r < 32; ++r) {        // second read hits L2/L3
        float4 x = vb[(size_t)(r0 + r)*16 + c0];
        run.x += x.x; run.y += x.y; run.z += x.z; run.w += x.w;
        ob[(size_t)(r0 + r)*16 + c0] = run;
    }
}

// ---------------------------------------------------------------------------
// K4a: scores + softmax fused.  Block = (bh, group of 4 ranks), one wave per
// rank, XCD-swizzled (k slice L2-resident).  Writes normalized weights
// (zeros past qrow).
// ---------------------------------------------------------------------------
__global__ __launch_bounds__(256) void scores_kernel(
    const float* __restrict__ q, const float* __restrict__ k,
    const int* __restrict__ idxSel, float* __restrict__ attn)
{
    __shared__ float4 kbuf[16 * 129];   // [g][j], stride 129 f4
    int b = blockIdx.x;
    int xcd = b & 7, s = b >> 3;          // s in 0..79
    int bh  = xcd + ((s / 10) << 3);
    int grp = s % 10;
    int qi = threadIdx.x >> 6, sub = threadIdx.x & 63;
    int rank = grp*4 + qi;
    int qrow = idxSel[bh*NS + rank];

    const float4* qrp = (const float4*)(q + ((size_t)bh * L_ + qrow) * D_);
    float4 qreg[16];
    #pragma unroll
    for (int g = 0; g < 16; ++g) qreg[g] = qrp[g];    // wave-uniform

    const float4* kb = (const float4*)(k + (size_t)bh * L_ * D_);
    float sc0[16], sc1[16];

    #pragma unroll
    for (int c = 0; c < 16; ++c) {
        __syncthreads();                               // kbuf reuse guard
        int j0 = c * 128;
        #pragma unroll
        for (int it = 0; it < 8; ++it) {               // coalesced stage
            int fi = threadIdx.x + 256*it;
            int g = fi & 15, j = fi >> 4;
            kbuf[g*129 + j] = kb[(size_t)(j0 + j)*16 + g];
        }
        __syncthreads();
        float acc0 = 0.f, acc1 = 0.f;
        #pragma unroll
        for (int g = 0; g < 16; ++g) {
            float4 k0 = kbuf[g*129 + sub];             // dense b128
            float4 k1 = kbuf[g*129 + sub + 64];
            float4 qq = qreg[g];
            acc0 += qq.x*k0.x + qq.y*k0.y + qq.z*k0.z + qq.w*k0.w;
            acc1 += qq.x*k1.x + qq.y*k1.y + qq.z*k1.z + qq.w*k1.w;
        }
        sc0[c] = acc0 * SCALE;
        sc1[c] = acc1 * SCALE;
    }

    // masked softmax, wave-local (row lives in sc0/sc1)
    float mx = -FLT_MAX;
    #pragma unroll
    for (int c = 0; c < 16; ++c) {
        if (c*128 + sub      <= qrow) mx = fmaxf(mx, sc0[c]);
        if (c*128 + sub + 64 <= qrow) mx = fmaxf(mx, sc1[c]);
    }
    #pragma unroll
    for (int off = 32; off; off >>= 1) mx = fmaxf(mx, __shfl_xor(mx, off, 64));

    float sum = 0.f;
    #pragma unroll
    for (int c = 0; c < 16; ++c) {
        sc0[c] = (c*128 + sub      <= qrow) ? __expf(sc0[c] - mx) : 0.f;
        sc1[c] = (c*128 + sub + 64 <= qrow) ? __expf(sc1[c] - mx) : 0.f;
        sum += sc0[c] + sc1[c];
    }
    #pragma unroll
    for (int off = 32; off; off >>= 1) sum += __shfl_xor(sum, off, 64);
    float inv = 1.f / sum;

    float* arow = attn + (size_t)(bh*NS + rank) * L_;
    #pragma unroll
    for (int c = 0; c < 16; ++c) {
        arow[c*128 + sub]      = sc0[c] * inv;         // coalesced
        arow[c*128 + sub + 64] = sc1[c] * inv;
    }
}

// ---------------------------------------------------------------------------
// K4b: out[bh, qrow_r, :] = attn_row_r @ v for 4 ranks per block,
// XCD-swizzled (v + attn slices L2-resident).
// ---------------------------------------------------------------------------
__global__ __launch_bounds__(256) void pv_kernel(
    const float* __restrict__ v, const int* __restrict__ idxSel,
    const float* __restrict__ attn, float* __restrict__ out)
{
    __shared__ float wl[4][L_ + 64];    // per-rank weights, j + 4*(j>>7) pad
    __shared__ float4 part[16][16];
    __shared__ int qr4[4];
    int b = blockIdx.x;
    int xcd = b & 7, s = b >> 3;          // s in 0..79
    int bh  = xcd + ((s / 10) << 3);
    int grp = s % 10;
    int t = threadIdx.x;
    if (t < 4) qr4[t] = idxSel[bh*NS + grp*4 + t];

    // stage 4 weight rows (coalesced f4 loads)
    #pragma unroll
    for (int it = 0; it < 8; ++it) {
        int f = t + 256*it;             // 0..2047 f4 across 4 rows
        int rr = f >> 9, fi = f & 511;
        const float4* ar = (const float4*)(attn + (size_t)(bh*NS + grp*4 + rr) * L_);
        float4 x = ar[fi];
        int j = 4*fi;
        *((float4*)&wl[rr][j + 4*(j >> 7)]) = x;
    }
    __syncthreads();

    int maxq = max(max(qr4[0], qr4[1]), max(qr4[2], qr4[3]));
    int d4 = t & 15, seg = t >> 4;
    const float4* vb = (const float4*)(v + (size_t)bh * L_ * D_);
    float4 acc[4];
    #pragma unroll
    for (int rr = 0; rr < 4; ++rr) acc[rr] = make_float4(0,0,0,0);

    int jlo = seg*128, jhi = min(jlo + 127, maxq);
    for (int j = jlo; j <= jhi; ++j) {
        float4 x = vb[(size_t)j*16 + d4];          // read once
        int jp = j + 4*(j >> 7);
        #pragma unroll
        for (int rr = 0; rr < 4; ++rr) {
            float wgt = wl[rr][jp];                // 2-way conflict (free)
            acc[rr].x += wgt*x.x; acc[rr].y += wgt*x.y;
            acc[rr].z += wgt*x.z; acc[rr].w += wgt*x.w;
        }
    }

    #pragma unroll
    for (int rr = 0; rr < 4; ++rr) {
        part[seg][d4] = acc[rr];
        __syncthreads();
        float4 a = acc[rr];
        for (int s2 = 8; s2; s2 >>= 1) {
            if (seg < s2) {
                float4 o = part[seg + s2][d4];
                a.x += o.x; a.y += o.y; a.z += o.z; a.w += o.w;
                part[seg][d4] = a;
            }
            __syncthreads();
        }
        if (seg == 0) {
            float4* orow = (float4*)(out + ((size_t)bh * L_ + qr4[rr]) * D_);
            orow[d4] = a;
        }
        __syncthreads();                // before part reuse
    }
}

// ---------------------------------------------------------------------------
extern "C" void kernel_launch(void* const* d_in, const int* in_sizes, int n_in,
                              void* d_out, int out_size, void* d_ws, size_t ws_size,
                              hipStream_t stream) {
    const float* q    = (const float*)d_in[0];
    const float* k    = (const float*)d_in[1];
    const float* v    = (const float*)d_in[2];
    const int*   ridx = (const int*)d_in[3];

    float* out     = (float*)d_out;                    // (B,H,L,D)
    float* attnOut = out + (size_t)BH * L_ * D_;       // (B,H,NS,L)

    float*  measure = (float*)d_ws;                                          // BH*L floats
    int*    idxSel  = (int*)((char*)d_ws + (size_t)BH * L_ * sizeof(float)); // BH*NS ints

    measure_kernel<<<BH * L_ / 4, 256, 0, stream>>>(q, k, ridx, measure);
    topk_kernel   <<<BH,          256, 0, stream>>>(measure, idxSel);
    cumsum_fused  <<<BH * 4,      256, 0, stream>>>(v, out);
    scores_kernel <<<BH * 10,     256, 0, stream>>>(q, k, idxSel, attnOut);
    pv_kernel     <<<BH * 10,     256, 0, stream>>>(v, idxSel, attnOut, out);
}

// Round 6
// 324.959 us; speedup vs baseline: 1.1295x; 1.0030x over previous
//
#include <hip/hip_runtime.h>
#include <float.h>
#include <math.h>

#define B_  8
#define H_  8
#define L_  2048
#define D_  64
#define NS  40          // num selected = min(5*ceil(ln(2048)), 2048) = 40
#define BH  (B_*H_)
#define SCALE 0.125f    // d^-0.5

// XCD swizzle: MI355X dispatches block b to XCD (b % 8).  We remap so that
// bh % 8 == b % 8 for every kernel -> all blocks of one bh run on one XCD,
// keeping that bh's k/v/measure/attn slices resident in its 4MB L2.

// DPP helper: x += lane_shifted_down_by<SHR>(x), within rows of 16 lanes,
// out-of-row reads return 0 (bound_ctrl).  Pure VALU - no LDS pipe.
template<int CTRL>
__device__ __forceinline__ float dpp_add(float x) {
    int s = __builtin_amdgcn_update_dpp(0, __float_as_int(x), CTRL, 0xF, 0xF, true);
    return x + __int_as_float(s);
}

// ---------------------------------------------------------------------------
// K1: sparsity measure.  One wave per query.  Octet (8 lanes x 2 f4) reads one
// k row; 5 passes cover 40 samples.  Bound by L2 random-line throughput
// (~160 64B lines/wave from the gather; VMEM instr-count cut in R6 changed
// nothing -> line/BW model, not TA-instr model).  Next lever would be
// cross-query k-row reuse via LDS tiling (deferred).
// ---------------------------------------------------------------------------
__global__ __launch_bounds__(256) void measure_kernel(
    const float* __restrict__ q, const float* __restrict__ k,
    const int* __restrict__ ridx, float* __restrict__ measure)
{
    int wave = threadIdx.x >> 6, lane = threadIdx.x & 63;
    int b = blockIdx.x;
    int xcd = b & 7, s = b >> 3;          // s in 0..4095
    int bh  = xcd + ((s >> 9) << 3);      // 8 bh per XCD, sequential
    int i   = (s & 511) * 4 + wave;       // query row within bh
    int oct = lane >> 3;                  // octet id 0..7 (row owner)
    int e   = lane & 7;                   // f4 slot within half-row

    // octet o handles samples 4o..4o+3 (one aligned int4) and 32+o (int).
    int4 r4 = *(const int4*)(ridx + i * NS + oct * 4);
    int  r5 = ridx[i * NS + 32 + oct];
    int rr[5] = { r4.x, r4.y, r4.z, r4.w, r5 };

    const float4* kb = (const float4*)(k + (size_t)bh * L_ * D_);
    const float4* qp = (const float4*)(q + ((size_t)bh * L_ + i) * D_);
    float4 qa = qp[e];          // dims 4e .. 4e+3
    float4 qb = qp[e + 8];      // dims 32+4e .. 32+4e+3

    float mx = -FLT_MAX, sm = 0.f;
    #pragma unroll
    for (int p = 0; p < 5; ++p) {
        int base = rr[p] << 4;                   // f4 index of row start
        float4 ka = kb[base + e];                // 8 lanes cover half the row
        float4 kc = kb[base + 8 + e];            // ... and the other half
        float pa = qa.x*ka.x + qa.y*ka.y + qa.z*ka.z + qa.w*ka.w;
        float pb = qb.x*kc.x + qb.y*kc.y + qb.z*kc.z + qb.w*kc.w;
        float pp = pa + pb;                      // 8-dim partial per lane
        // octet tree-sum: after shr1/2/4, lane 8o+7 = full dot(q, k[r])
        pp = dpp_add<0x111>(pp);                 // row_shr:1
        pp = dpp_add<0x112>(pp);                 // row_shr:2
        pp = dpp_add<0x114>(pp);                 // row_shr:4
        mx = fmaxf(mx, pp);                      // valid only in holder lanes
        sm += pp;
    }
    // holder lanes {7,15,...,63} each carry stats over their 5 samples;
    // xor partners of holders are holders, so 3 xor steps combine all 8.
    mx = fmaxf(mx, __shfl_xor(mx,  8, 64));  sm += __shfl_xor(sm,  8, 64);
    mx = fmaxf(mx, __shfl_xor(mx, 16, 64));  sm += __shfl_xor(sm, 16, 64);
    mx = fmaxf(mx, __shfl_xor(mx, 32, 64));  sm += __shfl_xor(sm, 32, 64);
    if (lane == 7)
        measure[(size_t)bh * L_ + i] = mx - sm * (1.0f / (float)L_);
}

// ---------------------------------------------------------------------------
// K2: top-NS per (b,h).  R8: barrier-free segmented tournament.  The old
// 256-thread version cost ~41us (40 rounds x 3 syncthreads + serial t==0
// scans, differential accounting R3 vs R4).  New: each wave extracts its
// 512-row segment's sorted top-40 IN-WAVE (zero barriers), then one barrier
// and wave 0 merges the 4 sorted lists with register-held heads.
// Comparator everywhere: (value desc, index asc) == lax.top_k tie rule.
// ---------------------------------------------------------------------------
__global__ __launch_bounds__(256) void topk_kernel(
    const float* __restrict__ measure, int* __restrict__ idxOut)
{
    __shared__ float segVal[4][NS];
    __shared__ int   segIdx[4][NS];
    int bh = blockIdx.x;
    int t = threadIdx.x, w = t >> 6, lane = t & 63;
    const float4* m4 = (const float4*)(measure + (size_t)bh * L_);

    // wave w owns rows [512w, 512w+512): f4 indices 128w + 0..127
    float vals[8];
    float4 a  = m4[128*w + 2*lane];
    float4 bb = m4[128*w + 2*lane + 1];
    vals[0]=a.x;  vals[1]=a.y;  vals[2]=a.z;  vals[3]=a.w;
    vals[4]=bb.x; vals[5]=bb.y; vals[6]=bb.z; vals[7]=bb.w;
    int gbase = 512*w + 8*lane;

    float lv = -FLT_MAX; int li = 0x7fffffff;
    #pragma unroll
    for (int e = 0; e < 8; ++e)
        if (vals[e] > lv) { lv = vals[e]; li = gbase + e; }  // strict >: lower idx wins ties

    for (int r = 0; r < NS; ++r) {
        float v = lv; int idx = li;
        #pragma unroll
        for (int off = 32; off; off >>= 1) {     // in-wave butterfly, no barriers
            float ov = __shfl_xor(v, off, 64);
            int   oi = __shfl_xor(idx, off, 64);
            if (ov > v || (ov == v && oi < idx)) { v = ov; idx = oi; }
        }
        if (lane == 0) { segVal[w][r] = v; segIdx[w][r] = idx; }
        // owner lane invalidates winner and rescans its 8 values
        if (((idx >> 3) & 63) == lane) {
            int slot = idx & 7;
            #pragma unroll
            for (int e = 0; e < 8; ++e) if (e == slot) vals[e] = -FLT_MAX;
            lv = -FLT_MAX; li = 0x7fffffff;
            #pragma unroll
            for (int e = 0; e < 8; ++e)
                if (vals[e] > lv) { lv = vals[e]; li = gbase + e; }
        }
    }
    __syncthreads();

    if (w == 0) {
        // 4-way merge of sorted lists; lanes mirror s = lane&3 (no divergence)
        int s = lane & 3;
        int h = 0;
        float hv = segVal[s][0]; int hi_ = segIdx[s][0];
        for (int r = 0; r < NS; ++r) {
            float v = hv; int idx = hi_; int ws = s;
            float ov = __shfl_xor(v, 1, 64); int oi = __shfl_xor(idx, 1, 64); int os = __shfl_xor(ws, 1, 64);
            if (ov > v || (ov == v && oi < idx)) { v = ov; idx = oi; ws = os; }
            ov = __shfl_xor(v, 2, 64); oi = __shfl_xor(idx, 2, 64); os = __shfl_xor(ws, 2, 64);
            if (ov > v || (ov == v && oi < idx)) { v = ov; idx = oi; ws = os; }
            if (lane == 0) idxOut[bh*NS + r] = idx;
            if (s == ws) {                        // winning segment advances
                ++h;
                if (h < NS) { hv = segVal[s][h]; hi_ = segIdx[s][h]; }
                else        { hv = -FLT_MAX;     hi_ = 0x7fffffff;  }
            }
        }
    }
}

// ---------------------------------------------------------------------------
// K3: cumsum(v) along L.  Fused single kernel, 256 blocks = bh x 4
// column-groups (4 f4 cols each), XCD-swizzled.
// ---------------------------------------------------------------------------
__global__ __launch_bounds__(256) void cumsum_fused(
    const float* __restrict__ v, float* __restrict__ out)
{
    __shared__ float4 part[64][5];        // [sub][col], pad 4->5 (bank spread)
    int b = blockIdx.x;
    int xcd = b & 7, s = b >> 3;          // s in 0..31
    int bh  = xcd + ((s >> 2) << 3);      // 8 bh per XCD
    int cg  = s & 3;                      // column group: f4 cols 4cg..4cg+3
    int col = threadIdx.x & 3, sub = threadIdx.x >> 2;   // sub 0..63
    int c0 = cg*4 + col;                  // f4 column 0..15
    int r0 = sub * 32;                    // stripe start row
    const float4* vb = (const float4*)(v + (size_t)bh * L_ * D_);
    float4*       ob = (float4*)(out + (size_t)bh * L_ * D_);

    float4 acc = make_float4(0,0,0,0);
    #pragma unroll
    for (int r = 0; r < 32; ++r) {
        float4 x = vb[(size_t)(r0 + r)*16 + c0];
        acc.x += x.x; acc.y += x.y; acc.z += x.z; acc.w += x.w;
    }
    part[sub][col] = acc;
    __syncthreads();

    float4 run = make_float4(0,0,0,0);    // exclusive prefix of stripes 0..sub-1
    for (int cc = 0; cc < sub; ++cc) {
        float4 x = part[cc][col];
        run.x += x.x; run.y += x.y; run.z += x.z; run.w += x.w;
    }

    #pragma unroll
    for (int r = 0; r < 32; ++r) {
        float4 x = vb[(size_t)(r0 + r)*16 + c0];
        run.x += x.x; run.y += x.y; run.z += x.z; run.w += x.w;
        ob[(size_t)(r0 + r)*16 + c0] = run;
    }
}

// ---------------------------------------------------------------------------
// K4a: scores + softmax fused.  Block = (bh, group of 4 ranks), one wave per
// rank, XCD-swizzled (k slice L2-resident).  Writes normalized weights
// (zeros past qrow).
// ---------------------------------------------------------------------------
__global__ __launch_bounds__(256) void scores_kernel(
    const float* __restrict__ q, const float* __restrict__ k,
    const int* __restrict__ idxSel, float* __restrict__ attn)
{
    __shared__ float4 kbuf[16 * 129];   // [g][j], stride 129 f4
    int b = blockIdx.x;
    int xcd = b & 7, s = b >> 3;          // s in 0..79
    int bh  = xcd + ((s / 10) << 3);
    int grp = s % 10;
    int qi = threadIdx.x >> 6, sub = threadIdx.x & 63;
    int rank = grp*4 + qi;
    int qrow = idxSel[bh*NS + rank];

    const float4* qrp = (const float4*)(q + ((size_t)bh * L_ + qrow) * D_);
    float4 qreg[16];
    #pragma unroll
    for (int g = 0; g < 16; ++g) qreg[g] = qrp[g];    // wave-uniform

    const float4* kb = (const float4*)(k + (size_t)bh * L_ * D_);
    float sc0[16], sc1[16];

    #pragma unroll
    for (int c = 0; c < 16; ++c) {
        __syncthreads();                               // kbuf reuse guard
        int j0 = c * 128;
        #pragma unroll
        for (int it = 0; it < 8; ++it) {               // coalesced stage
            int fi = threadIdx.x + 256*it;
            int g = fi & 15, j = fi >> 4;
            kbuf[g*129 + j] = kb[(size_t)(j0 + j)*16 + g];
        }
        __syncthreads();
        float acc0 = 0.f, acc1 = 0.f;
        #pragma unroll
        for (int g = 0; g < 16; ++g) {
            float4 k0 = kbuf[g*129 + sub];             // dense b128
            float4 k1 = kbuf[g*129 + sub + 64];
            float4 qq = qreg[g];
            acc0 += qq.x*k0.x + qq.y*k0.y + qq.z*k0.z + qq.w*k0.w;
            acc1 += qq.x*k1.x + qq.y*k1.y + qq.z*k1.z + qq.w*k1.w;
        }
        sc0[c] = acc0 * SCALE;
        sc1[c] = acc1 * SCALE;
    }

    // masked softmax, wave-local (row lives in sc0/sc1)
    float mx = -FLT_MAX;
    #pragma unroll
    for (int c = 0; c < 16; ++c) {
        if (c*128 + sub      <= qrow) mx = fmaxf(mx, sc0[c]);
        if (c*128 + sub + 64 <= qrow) mx = fmaxf(mx, sc1[c]);
    }
    #pragma unroll
    for (int off = 32; off; off >>= 1) mx = fmaxf(mx, __shfl_xor(mx, off, 64));

    float sum = 0.f;
    #pragma unroll
    for (int c = 0; c < 16; ++c) {
        sc0[c] = (c*128 + sub      <= qrow) ? __expf(sc0[c] - mx) : 0.f;
        sc1[c] = (c*128 + sub + 64 <= qrow) ? __expf(sc1[c] - mx) : 0.f;
        sum += sc0[c] + sc1[c];
    }
    #pragma unroll
    for (int off = 32; off; off >>= 1) sum += __shfl_xor(sum, off, 64);
    float inv = 1.f / sum;

    float* arow = attn + (size_t)(bh*NS + rank) * L_;
    #pragma unroll
    for (int c = 0; c < 16; ++c) {
        arow[c*128 + sub]      = sc0[c] * inv;         // coalesced
        arow[c*128 + sub + 64] = sc1[c] * inv;
    }
}

// ---------------------------------------------------------------------------
// K4b: out[bh, qrow_r, :] = attn_row_r @ v for 4 ranks per block,
// XCD-swizzled (v + attn slices L2-resident).
// ---------------------------------------------------------------------------
__global__ __launch_bounds__(256) void pv_kernel(
    const float* __restrict__ v, const int* __restrict__ idxSel,
    const float* __restrict__ attn, float* __restrict__ out)
{
    __shared__ float wl[4][L_ + 64];    // per-rank weights, j + 4*(j>>7) pad
    __shared__ float4 part[16][16];
    __shared__ int qr4[4];
    int b = blockIdx.x;
    int xcd = b & 7, s = b >> 3;          // s in 0..79
    int bh  = xcd + ((s / 10) << 3);
    int grp = s % 10;
    int t = threadIdx.x;
    if (t < 4) qr4[t] = idxSel[bh*NS + grp*4 + t];

    // stage 4 weight rows (coalesced f4 loads)
    #pragma unroll
    for (int it = 0; it < 8; ++it) {
        int f = t + 256*it;             // 0..2047 f4 across 4 rows
        int rr = f >> 9, fi = f & 511;
        const float4* ar = (const float4*)(attn + (size_t)(bh*NS + grp*4 + rr) * L_);
        float4 x = ar[fi];
        int j = 4*fi;
        *((float4*)&wl[rr][j + 4*(j >> 7)]) = x;
    }
    __syncthreads();

    int maxq = max(max(qr4[0], qr4[1]), max(qr4[2], qr4[3]));
    int d4 = t & 15, seg = t >> 4;
    const float4* vb = (const float4*)(v + (size_t)bh * L_ * D_);
    float4 acc[4];
    #pragma unroll
    for (int rr = 0; rr < 4; ++rr) acc[rr] = make_float4(0,0,0,0);

    int jlo = seg*128, jhi = min(jlo + 127, maxq);
    for (int j = jlo; j <= jhi; ++j) {
        float4 x = vb[(size_t)j*16 + d4];          // read once
        int jp = j + 4*(j >> 7);
        #pragma unroll
        for (int rr = 0; rr < 4; ++rr) {
            float wgt = wl[rr][jp];                // 2-way conflict (free)
            acc[rr].x += wgt*x.x; acc[rr].y += wgt*x.y;
            acc[rr].z += wgt*x.z; acc[rr].w += wgt*x.w;
        }
    }

    #pragma unroll
    for (int rr = 0; rr < 4; ++rr) {
        part[seg][d4] = acc[rr];
        __syncthreads();
        float4 a = acc[rr];
        for (int s2 = 8; s2; s2 >>= 1) {
            if (seg < s2) {
                float4 o = part[seg + s2][d4];
                a.x += o.x; a.y += o.y; a.z += o.z; a.w += o.w;
                part[seg][d4] = a;
            }
            __syncthreads();
        }
        if (seg == 0) {
            float4* orow = (float4*)(out + ((size_t)bh * L_ + qr4[rr]) * D_);
            orow[d4] = a;
        }
        __syncthreads();                // before part reuse
    }
}

// ---------------------------------------------------------------------------
extern "C" void kernel_launch(void* const* d_in, const int* in_sizes, int n_in,
                              void* d_out, int out_size, void* d_ws, size_t ws_size,
                              hipStream_t stream) {
    const float* q    = (const float*)d_in[0];
    const float* k    = (const float*)d_in[1];
    const float* v    = (const float*)d_in[2];
    const int*   ridx = (const int*)d_in[3];

    float* out     = (float*)d_out;                    // (B,H,L,D)
    float* attnOut = out + (size_t)BH * L_ * D_;       // (B,H,NS,L)

    float*  measure = (float*)d_ws;                                          // BH*L floats
    int*    idxSel  = (int*)((char*)d_ws + (size_t)BH * L_ * sizeof(float)); // BH*NS ints

    measure_kernel<<<BH * L_ / 4, 256, 0, stream>>>(q, k, ridx, measure);
    topk_kernel   <<<BH,          256, 0, stream>>>(measure, idxSel);
    cumsum_fused  <<<BH * 4,      256, 0, stream>>>(v, out);
    scores_kernel <<<BH * 10,     256, 0, stream>>>(q, k, idxSel, attnOut);
    pv_kernel     <<<BH * 10,     256, 0, stream>>>(v, idxSel, attnOut, out);
}